// Round 1
// baseline (146.418 us; speedup 1.0000x reference)
//
#include <hip/hip_runtime.h>

typedef float f32x4 __attribute__((ext_vector_type(4)));
typedef __bf16 bf16x8 __attribute__((ext_vector_type(8)));

#define H_DIM 4096
#define I_DIM 11008
#define NSPLIT1 4
#define NSPLIT2 8
#define K1_PER (H_DIM / NSPLIT1)   // 1024 -> 32 mfma-iters
#define K2_PER (I_DIM / NSPLIT2)   // 1376 -> 43 mfma-iters

// 2:4 prune of one contiguous group of 4 (matches jnp.argsort stable-tie
// semantics: keep element i iff #{j: |wj|<|wi| or (|wj|==|wi| and j<i)} >= 2)
__device__ __forceinline__ f32x4 prune4(f32x4 w) {
    float a0 = fabsf(w[0]), a1 = fabsf(w[1]), a2 = fabsf(w[2]), a3 = fabsf(w[3]);
    int r0 = (int)(a1 < a0) + (int)(a2 < a0) + (int)(a3 < a0);
    int r1 = (int)(a0 <= a1) + (int)(a2 < a1) + (int)(a3 < a1);
    int r2 = (int)(a0 <= a2) + (int)(a1 <= a2) + (int)(a3 < a2);
    int r3 = (int)(a0 <= a3) + (int)(a1 <= a3) + (int)(a2 <= a3);
    w[0] = (r0 >= 2) ? w[0] : 0.0f;
    w[1] = (r1 >= 2) ? w[1] : 0.0f;
    w[2] = (r2 >= 2) ? w[2] : 0.0f;
    w[3] = (r3 >= 2) ? w[3] : 0.0f;
    return w;
}

__device__ __forceinline__ bf16x8 cvt8(f32x4 a, f32x4 b) {
    bf16x8 r;
    r[0] = (__bf16)a[0]; r[1] = (__bf16)a[1];
    r[2] = (__bf16)a[2]; r[3] = (__bf16)a[3];
    r[4] = (__bf16)b[0]; r[5] = (__bf16)b[1];
    r[6] = (__bf16)b[2]; r[7] = (__bf16)b[3];
    return r;
}

__global__ __launch_bounds__(256) void k_cvt_x(const float* __restrict__ x,
                                               __bf16* __restrict__ xb) {
    int i = (blockIdx.x * 256 + threadIdx.x) * 4;
    f32x4 v = *(const f32x4*)(x + i);
    xb[i + 0] = (__bf16)v[0]; xb[i + 1] = (__bf16)v[1];
    xb[i + 2] = (__bf16)v[2]; xb[i + 3] = (__bf16)v[3];
}

// gate+up fused: each wave = 16 output cols x 32 tokens, k-split via blockIdx.y
__global__ __launch_bounds__(256) void k_gateup(
        const float* __restrict__ GW, const float* __restrict__ UW,
        const __bf16* __restrict__ XB,
        float* __restrict__ gpart, float* __restrict__ upart) {
    const int lane = threadIdx.x & 63;
    const int wv   = threadIdx.x >> 6;
    const int i0   = (blockIdx.x * 4 + wv) * 16;   // 688 tiles * 16 = 11008
    const int s    = blockIdx.y;
    const int kbeg = s * K1_PER;
    const int lrow = lane & 15;
    const int lk   = (lane >> 4) << 3;

    const float*  gp  = GW + (size_t)(i0 + lrow) * H_DIM + kbeg + lk;
    const float*  up  = UW + (size_t)(i0 + lrow) * H_DIM + kbeg + lk;
    const __bf16* xp0 = XB + (size_t)lrow * H_DIM + kbeg + lk;
    const __bf16* xp1 = xp0 + (size_t)16 * H_DIM;

    f32x4 aG0 = {0,0,0,0}, aG1 = {0,0,0,0}, aU0 = {0,0,0,0}, aU1 = {0,0,0,0};

    #pragma unroll 2
    for (int it = 0; it < K1_PER / 32; ++it) {
        const int ko = it * 32;
        f32x4 g0 = *(const f32x4*)(gp + ko);
        f32x4 g1 = *(const f32x4*)(gp + ko + 4);
        f32x4 u0 = *(const f32x4*)(up + ko);
        f32x4 u1 = *(const f32x4*)(up + ko + 4);
        bf16x8 a0 = *(const bf16x8*)(xp0 + ko);
        bf16x8 a1 = *(const bf16x8*)(xp1 + ko);
        bf16x8 bg = cvt8(prune4(g0), prune4(g1));
        bf16x8 bu = cvt8(prune4(u0), prune4(u1));
        aG0 = __builtin_amdgcn_mfma_f32_16x16x32_bf16(a0, bg, aG0, 0, 0, 0);
        aG1 = __builtin_amdgcn_mfma_f32_16x16x32_bf16(a1, bg, aG1, 0, 0, 0);
        aU0 = __builtin_amdgcn_mfma_f32_16x16x32_bf16(a0, bu, aU0, 0, 0, 0);
        aU1 = __builtin_amdgcn_mfma_f32_16x16x32_bf16(a1, bu, aU1, 0, 0, 0);
    }

    const int col = i0 + lrow;
    const int t0  = (lane >> 4) * 4;          // C/D: col=lane&15, row=(lane>>4)*4+r
    const size_t srow = (size_t)s * 32;
    #pragma unroll
    for (int r = 0; r < 4; ++r) {
        size_t iA = (srow + t0 + r) * I_DIM + col;
        size_t iB = (srow + t0 + 16 + r) * I_DIM + col;
        gpart[iA] = aG0[r];  gpart[iB] = aG1[r];
        upart[iA] = aU0[r];  upart[iB] = aU1[r];
    }
}

__global__ __launch_bounds__(256) void k_hidden(
        const float* __restrict__ gpart, const float* __restrict__ upart,
        const float* __restrict__ gb, const float* __restrict__ ub,
        __bf16* __restrict__ hb) {
    const int i = blockIdx.x * 256 + threadIdx.x;  // 43*256 = 11008
    const int t = blockIdx.y;
    float g = gb[i], u = ub[i];
    #pragma unroll
    for (int s = 0; s < NSPLIT1; ++s) {
        g += gpart[(size_t)(s * 32 + t) * I_DIM + i];
        u += upart[(size_t)(s * 32 + t) * I_DIM + i];
    }
    float h = g / (1.0f + __expf(-g)) * u;   // silu(g)*u
    hb[(size_t)t * I_DIM + i] = (__bf16)h;
}

__global__ __launch_bounds__(256) void k_down(
        const float* __restrict__ DW, const __bf16* __restrict__ HB,
        float* __restrict__ opart) {
    const int lane = threadIdx.x & 63;
    const int wv   = threadIdx.x >> 6;
    const int o0   = (blockIdx.x * 4 + wv) * 16;   // 256 tiles * 16 = 4096
    const int s    = blockIdx.y;
    const int kbeg = s * K2_PER;
    const int lrow = lane & 15;
    const int lk   = (lane >> 4) << 3;

    const float*  dp  = DW + (size_t)(o0 + lrow) * I_DIM + kbeg + lk;
    const __bf16* hp0 = HB + (size_t)lrow * I_DIM + kbeg + lk;
    const __bf16* hp1 = hp0 + (size_t)16 * I_DIM;

    f32x4 acc0 = {0,0,0,0}, acc1 = {0,0,0,0};

    #pragma unroll 2
    for (int it = 0; it < K2_PER / 32; ++it) {
        const int ko = it * 32;
        f32x4 d0 = *(const f32x4*)(dp + ko);
        f32x4 d1 = *(const f32x4*)(dp + ko + 4);
        bf16x8 h0 = *(const bf16x8*)(hp0 + ko);
        bf16x8 h1 = *(const bf16x8*)(hp1 + ko);
        bf16x8 bw = cvt8(d0, d1);
        acc0 = __builtin_amdgcn_mfma_f32_16x16x32_bf16(h0, bw, acc0, 0, 0, 0);
        acc1 = __builtin_amdgcn_mfma_f32_16x16x32_bf16(h1, bw, acc1, 0, 0, 0);
    }

    const int col = o0 + lrow;
    const int t0  = (lane >> 4) * 4;
    const size_t srow = (size_t)s * 32;
    #pragma unroll
    for (int r = 0; r < 4; ++r) {
        opart[(srow + t0 + r) * H_DIM + col]      = acc0[r];
        opart[(srow + t0 + 16 + r) * H_DIM + col] = acc1[r];
    }
}

__global__ __launch_bounds__(256) void k_out(
        const float* __restrict__ opart, const float* __restrict__ db,
        float* __restrict__ out) {
    const int o = blockIdx.x * 256 + threadIdx.x;  // 16*256 = 4096
    const int t = blockIdx.y;
    float v = db[o];
    #pragma unroll
    for (int s = 0; s < NSPLIT2; ++s)
        v += opart[(size_t)(s * 32 + t) * H_DIM + o];
    out[(size_t)t * H_DIM + o] = v;
}

extern "C" void kernel_launch(void* const* d_in, const int* in_sizes, int n_in,
                              void* d_out, int out_size, void* d_ws, size_t ws_size,
                              hipStream_t stream) {
    const float* x  = (const float*)d_in[0];
    const float* gw = (const float*)d_in[1];
    const float* uw = (const float*)d_in[2];
    const float* dw = (const float*)d_in[3];
    const float* gb = (const float*)d_in[4];
    const float* ub = (const float*)d_in[5];
    const float* db = (const float*)d_in[6];
    float* out = (float*)d_out;

    char* ws = (char*)d_ws;
    const size_t XB_BYTES = (size_t)32 * H_DIM * 2;                  // 256 KiB
    const size_t HB_BYTES = (size_t)32 * I_DIM * 2;                  // 688 KiB
    const size_t GP_BYTES = (size_t)NSPLIT1 * 32 * I_DIM * 4;        // 5.4 MiB
    __bf16* xb    = (__bf16*)(ws);
    __bf16* hb    = (__bf16*)(ws + XB_BYTES);
    float*  gpart = (float*)(ws + XB_BYTES + HB_BYTES);
    float*  upart = (float*)(ws + XB_BYTES + HB_BYTES + GP_BYTES);
    float*  opart = (float*)(ws + XB_BYTES + HB_BYTES + 2 * GP_BYTES);
    // total ws use ~15.7 MiB

    k_cvt_x <<<dim3(128),          dim3(256), 0, stream>>>(x, xb);
    k_gateup<<<dim3(172, NSPLIT1), dim3(256), 0, stream>>>(gw, uw, xb, gpart, upart);
    k_hidden<<<dim3(43, 32),       dim3(256), 0, stream>>>(gpart, upart, gb, ub, hb);
    k_down  <<<dim3(64, NSPLIT2),  dim3(256), 0, stream>>>(dw, hb, opart);
    k_out   <<<dim3(16, 32),       dim3(256), 0, stream>>>(opart, db, out);
}